// Round 5
// baseline (170.941 us; speedup 1.0000x reference)
//
#include <hip/hip_runtime.h>
#include <cstddef>

#define T_STEPS 1024
#define BATCH   32768
#define G1      50
#define H1      32
#define G2      20
#define NSEG    8
#define SEGLEN  (T_STEPS / NSEG)   // 128

__device__ __forceinline__ float softplus_f(float x) {
    // jax.nn.softplus = max(x,0) + log1p(exp(-|x|))
    float e = __expf(-fabsf(x));
    return fmaxf(x, 0.0f) + __logf(1.0f + e);
}

// One BLOCK (1 wave, 64 lanes) per time step t. Writes a[t] = dt * beta(t).
__global__ __launch_bounds__(64) void beta_kernel(
    const float* __restrict__ t_steps,
    const float* __restrict__ grid1,      // [50]
    const float* __restrict__ spline_w1,  // [50, 32] (g, j)
    const float* __restrict__ base_w1,    // [32]
    const float* __restrict__ grid2,      // [20]
    const float* __restrict__ spline_w2,  // [640]  index j*20+g
    const float* __restrict__ base_w2,    // [32]
    float* __restrict__ a_out)            // [1024] out: dt*beta
{
    __shared__ float se[G1];
    __shared__ float sh[H1];

    const int t    = blockIdx.x;
    const int lane = threadIdx.x;
    const float x  = t_steps[t];

    if (lane < G1) {
        float d = x - grid1[lane];
        se[lane] = __expf(-10.0f * d * d);
    }
    __syncthreads();

    if (lane < H1) {
        float acc = x * base_w1[lane];
        #pragma unroll
        for (int g = 0; g < G1; ++g)
            acc = fmaf(se[g], spline_w1[g * H1 + lane], acc);  // LDS broadcast
        sh[lane] = acc;
    }
    __syncthreads();

    float acc = 0.0f;
    #pragma unroll
    for (int k = 0; k < 10; ++k) {
        int p = lane + 64 * k;        // 0..639
        int j = p / G2;
        int g = p - j * G2;
        float d = sh[j] - grid2[g];
        acc = fmaf(__expf(-10.0f * d * d), spline_w2[p], acc);
    }
    if (lane < H1) acc = fmaf(sh[lane], base_w2[lane], acc);

    #pragma unroll
    for (int ofs = 32; ofs >= 1; ofs >>= 1)
        acc += __shfl_xor(acc, ofs, 64);

    if (lane == 0) {
        float dt = t_steps[1] - t_steps[0];
        a_out[t] = dt * softplus_f(acc);
    }
}

// Phase A: store-free full recurrence; checkpoint (I,S) at t=128*s, s=1..7.
// ck layout: ck[(s-1)*BATCH + b] = I,  ck[(7 + s-1)*BATCH + b] = S.
__global__ __launch_bounds__(128) void prepass_kernel(
    const float* __restrict__ t_steps,
    const float* __restrict__ initial_I,
    const float* __restrict__ gamma_param,
    const float* __restrict__ a_in,   // [1024] dt*beta
    float* __restrict__ ck)           // [14 * BATCH]
{
    __shared__ float4 sa4[T_STEPS / 4];
    {
        const float4* g4 = (const float4*)a_in;
        #pragma unroll
        for (int i = 0; i < T_STEPS / 4 / 128; ++i)
            sa4[threadIdx.x + i * 128] = g4[threadIdx.x + i * 128];
    }
    __syncthreads();

    const int b = blockIdx.x * 128 + threadIdx.x;
    float I = initial_I[b];
    float S = 1.0f - I;
    const float gamma = softplus_f(gamma_param[0]);
    const float dt = t_steps[1] - t_steps[0];
    const float c = fmaf(-dt, gamma, 1.0f);   // 1 - dt*gamma

    #pragma unroll 1
    for (int s = 0; s < NSEG - 1; ++s) {      // segments 0..6; checkpoint after each
        #pragma unroll 1
        for (int tb = s * SEGLEN; tb < (s + 1) * SEGLEN; tb += 16) {
            float4 q[4];
            #pragma unroll
            for (int k = 0; k < 4; ++k) q[k] = sa4[tb / 4 + k];
            const float* av = (const float*)q;
            #pragma unroll
            for (int k = 0; k < 16; ++k) {
                float a  = av[k];
                float f  = fmaf(a, S, c);        // c + a*S   (old S)
                float u  = fmaf(-a, I, 1.0f);    // 1 - a*I   (old I)
                float In = I * f;
                float Sn = S * u;
                I = fminf(fmaxf(In, 0.0f), 5.0f);
                S = fminf(fmaxf(Sn, 0.0f), 5.0f);
            }
        }
        ck[(size_t)s * BATCH + b]                      = I;
        ck[(size_t)(NSEG - 1 + s) * BATCH + b]         = S;
    }
}

// Phase B: 2048 blocks (256 batch-chunks x 8 segments) = 16 waves/CU.
// Each block replays 128 steps from its checkpoint, storing I per step.
// Identical FP op order per batch element -> bitwise-same result.
__global__ __launch_bounds__(128) void replay_kernel(
    const float* __restrict__ t_steps,
    const float* __restrict__ initial_I,
    const float* __restrict__ gamma_param,
    const float* __restrict__ a_in,   // [1024] dt*beta
    const float* __restrict__ ck,     // [14 * BATCH]
    float* __restrict__ out)          // [T, B]
{
    __shared__ float sa[SEGLEN];
    const int s   = blockIdx.y;
    const int tid = threadIdx.x;
    sa[tid] = a_in[s * SEGLEN + tid];
    __syncthreads();

    const int b = blockIdx.x * 128 + tid;
    float I, S;
    if (s == 0) {
        I = initial_I[b];
        S = 1.0f - I;
    } else {
        I = ck[(size_t)(s - 1) * BATCH + b];
        S = ck[(size_t)(NSEG - 1 + s - 1) * BATCH + b];
    }
    const float gamma = softplus_f(gamma_param[0]);
    const float dt = t_steps[1] - t_steps[0];
    const float c = fmaf(-dt, gamma, 1.0f);   // 1 - dt*gamma

    float* outp = out + (size_t)s * SEGLEN * BATCH + b;

    #pragma unroll 1
    for (int tb = 0; tb < SEGLEN; tb += 16) {
        float4 q[4];
        #pragma unroll
        for (int k = 0; k < 4; ++k) q[k] = ((const float4*)sa)[tb / 4 + k];
        const float* av = (const float*)q;
        #pragma unroll
        for (int k = 0; k < 16; ++k) {
            float a  = av[k];
            float f  = fmaf(a, S, c);
            float u  = fmaf(-a, I, 1.0f);
            float In = I * f;
            float Sn = S * u;
            I = fminf(fmaxf(In, 0.0f), 5.0f);
            S = fminf(fmaxf(Sn, 0.0f), 5.0f);
            outp[(size_t)(tb + k) * BATCH] = I;
        }
    }
}

extern "C" void kernel_launch(void* const* d_in, const int* in_sizes, int n_in,
                              void* d_out, int out_size, void* d_ws, size_t ws_size,
                              hipStream_t stream) {
    const float* t_steps     = (const float*)d_in[0];
    const float* initial_I   = (const float*)d_in[1];
    const float* grid1       = (const float*)d_in[2];
    const float* spline_w1   = (const float*)d_in[3];
    const float* base_w1     = (const float*)d_in[4];
    const float* grid2       = (const float*)d_in[5];
    const float* spline_w2   = (const float*)d_in[6];
    const float* base_w2     = (const float*)d_in[7];
    const float* gamma_param = (const float*)d_in[8];
    float* out = (float*)d_out;
    float* a_t = (float*)d_ws;                       // 1024 floats: dt*beta(t)
    float* ck  = (float*)((char*)d_ws + 4096);       // 14*BATCH floats: checkpoints

    beta_kernel<<<T_STEPS, 64, 0, stream>>>(
        t_steps, grid1, spline_w1, base_w1, grid2, spline_w2, base_w2, a_t);
    prepass_kernel<<<BATCH / 128, 128, 0, stream>>>(
        t_steps, initial_I, gamma_param, a_t, ck);
    dim3 grid(BATCH / 128, NSEG);
    replay_kernel<<<grid, 128, 0, stream>>>(
        t_steps, initial_I, gamma_param, a_t, ck, out);
}